// Round 5
// baseline (87.927 us; speedup 1.0000x reference)
//
#include <hip/hip_runtime.h>
#include <hip/hip_bf16.h>
#include <math.h>

#define S_LEN 4096
#define N_FEAT 64
#define N_BATCH 16
#define N_SCALES 8
#define THRESH 1e-4f
#define PADL 2048
#define NCHUNK ((PADL + S_LEN) / 16)    // 384 chunks of 16 s-values
#define BCHUNK_ELEMS 1024               // [h:2][f:64][e:8] bf16 per 16-s chunk

typedef unsigned short ushort_t;
typedef __attribute__((ext_vector_type(8))) short bf16x8;
typedef __attribute__((ext_vector_type(16))) float f32x16;

struct ScaleParams {
    int L[N_SCALES], Mc[N_SCALES], Niter[N_SCALES], Aoff[N_SCALES]; // Aoff: ushort elems
    float inv_sqrt_scale[N_SCALES], step[N_SCALES];
};

// ---- prep: Toeplitz A-matrices in MFMA A-frag order, interp fused ------------
// Scale table: NC = Niter+8 chunks; chunk ci <-> conv chunk m = ci-6
// A_m[ti][sj] = kern[16m-16+ti-sj]; kern[l] = interp(mother, l*step)*inv_sqrt
__global__ void prep_A(const float* __restrict__ mother, ushort_t* __restrict__ Atab,
                       ScaleParams p, int totalA) {
    int i = blockIdx.x * blockDim.x + threadIdx.x;
    if (i >= totalA) return;
    int idx = 0;
#pragma unroll
    for (int s = 1; s < N_SCALES; ++s)
        if (i >= p.Aoff[s]) idx = s;
    int rel = i - p.Aoff[idx];
    int ci = rel >> 9;
    int r = rel & 511;
    int lane = r >> 3, e = r & 7;
    int ti = lane & 31, sj = 8 * (lane >> 5) + e;
    int kidx = 16 * (ci - 6) - 16 + ti - sj;
    float v = 0.f;
    if (kidx >= 0 && kidx < p.L[idx]) {
        float xq = fminf(kidx * p.step[idx], 63.0f);
        int i0 = (int)xq; if (i0 > 62) i0 = 62;
        float frac = xq - (float)i0;
        float a = mother[idx * 64 + i0];
        float b = mother[idx * 64 + i0 + 1];
        v = (a + (b - a) * frac) * p.inv_sqrt_scale[idx];
    }
    __hip_bfloat16 hh = __float2bfloat16(v);
    Atab[i] = *reinterpret_cast<ushort_t*>(&hh);
}

// ---- prep: signal [b][s][f] fp32 -> fragment-major XTc[b][G][f][e] bf16 ------
__global__ __launch_bounds__(256) void transpose_sig(const float* __restrict__ sig,
                                                     ushort_t* __restrict__ XTc) {
    const int b = blockIdx.y;
    const int G = blockIdx.x * 4 + (threadIdx.x >> 6);
    const int l = threadIdx.x & 63;
    unsigned int u[4];
    if (G < PADL / 8) {
        u[0] = u[1] = u[2] = u[3] = 0u;
    } else {
        const float* sp = sig + ((size_t)b * S_LEN + ((size_t)G * 8 - PADL)) * N_FEAT + l;
#pragma unroll
        for (int j = 0; j < 4; ++j) {
            float v0 = sp[(size_t)(2 * j) * N_FEAT];
            float v1 = sp[(size_t)(2 * j + 1) * N_FEAT];
            __hip_bfloat16 h0 = __float2bfloat16(v0);
            __hip_bfloat16 h1 = __float2bfloat16(v1);
            u[j] = (unsigned int)*reinterpret_cast<ushort_t*>(&h0) |
                   ((unsigned int)*reinterpret_cast<ushort_t*>(&h1) << 16);
        }
    }
    uint4 vv = {u[0], u[1], u[2], u[3]};
    *reinterpret_cast<uint4*>(XTc + (size_t)b * (NCHUNK * BCHUNK_ELEMS)
                              + (size_t)G * 512 + l * 8) = vv;
}

#define MFMA(A, X, C) C = __builtin_amdgcn_mfma_f32_32x32x16_bf16(A, X, C, 0, 0, 0)

// ---- main conv: 1 wave = 128 t x 64 f; A-ring(8) + depth-2 B prefetch --------
__global__ __launch_bounds__(256) void wavelet_mfma(
    const ushort_t* __restrict__ XTc, const ushort_t* __restrict__ Atab,
    const float* __restrict__ sw, float* __restrict__ out, ScaleParams p) {
    const int idx = 7 - blockIdx.z;            // longest scales dispatched first
    const int b = blockIdx.y;
    const int wave = threadIdx.x >> 6, lane = threadIdx.x & 63;
    const int tw0 = blockIdx.x * 512 + wave * 128;
    const int h = lane >> 5, fc = lane & 31;
    const int niter = p.Niter[idx];
    const int c0 = (PADL + tw0) / 16 + 1;

    const ushort_t* Ab = Atab + p.Aoff[idx] + lane * 8;              // A chunk ci: +ci*512
    const ushort_t* Bb = XTc + (size_t)b * (NCHUNK * BCHUNK_ELEMS)
                       + h * 512 + fc * 8;                            // B chunk c: +c*1024

    f32x16 c00, c01, c10, c11, c20, c21, c30, c31;
#pragma unroll
    for (int r = 0; r < 16; ++r) {
        c00[r] = 0.f; c01[r] = 0.f; c10[r] = 0.f; c11[r] = 0.f;
        c20[r] = 0.f; c21[r] = 0.f; c30[r] = 0.f; c31[r] = 0.f;
    }

    // preload A ring (chunks 0..7; 0..5 are the leading zero pad) and B depth-2
    bf16x8 Ar[8];
#pragma unroll
    for (int i = 0; i < 8; ++i)
        Ar[i] = *reinterpret_cast<const bf16x8*>(Ab + i * 512);
    bf16x8 Xe0 = *reinterpret_cast<const bf16x8*>(Bb + (size_t)(c0 + 6) * 1024);
    bf16x8 Xe1 = *reinterpret_cast<const bf16x8*>(Bb + (size_t)(c0 + 6) * 1024 + 256);
    bf16x8 Xo0 = *reinterpret_cast<const bf16x8*>(Bb + (size_t)(c0 + 5) * 1024);
    bf16x8 Xo1 = *reinterpret_cast<const bf16x8*>(Bb + (size_t)(c0 + 5) * 1024 + 256);

    const ushort_t* Apf = Ab + 8 * 512;                       // next A chunk (ci = n+8)
    const ushort_t* Bpf = Bb + (size_t)(c0 + 4) * 1024;       // B chunk for n+2

    for (int it = 0; it < niter; it += 8) {
#pragma unroll
        for (int ph = 0; ph < 8; ++ph) {
            bf16x8 a0 = Ar[ph & 7];          // chunk n      (subtile j=0)
            bf16x8 a1 = Ar[(ph + 2) & 7];    // chunk n+2    (j=1)
            bf16x8 a2 = Ar[(ph + 4) & 7];    // chunk n+4    (j=2)
            bf16x8 a3 = Ar[(ph + 6) & 7];    // chunk n+6    (j=3)
            bf16x8 x0 = (ph & 1) ? Xo0 : Xe0;
            bf16x8 x1 = (ph & 1) ? Xo1 : Xe1;
            // prefetch: A chunk n+8 into the slot freed this iter; B for n+2
            Ar[ph & 7] = *reinterpret_cast<const bf16x8*>(Apf);
            Apf += 512;
            if (ph & 1) {
                Xo0 = *reinterpret_cast<const bf16x8*>(Bpf);
                Xo1 = *reinterpret_cast<const bf16x8*>(Bpf + 256);
            } else {
                Xe0 = *reinterpret_cast<const bf16x8*>(Bpf);
                Xe1 = *reinterpret_cast<const bf16x8*>(Bpf + 256);
            }
            Bpf -= 1024;
            MFMA(a0, x0, c00); MFMA(a0, x1, c01);
            MFMA(a1, x0, c10); MFMA(a1, x1, c11);
            MFMA(a2, x0, c20); MFMA(a2, x1, c21);
            MFMA(a3, x0, c30); MFMA(a3, x1, c31);
        }
    }

    const float w = sw[idx];
    float* ob = out + ((size_t)(b * N_SCALES + idx) * S_LEN + tw0) * N_FEAT + fc;
#define STORE_TILE(CLO, CHI, JT)                                               \
    {                                                                          \
        _Pragma("unroll") for (int r = 0; r < 16; ++r) {                       \
            const int row = (JT) * 32 + (r & 3) + 8 * (r >> 2) + 4 * h;        \
            float v;                                                           \
            v = CLO[r] * w; v = (fabsf(v) > THRESH) ? v : 0.f;                 \
            __builtin_nontemporal_store(v, &ob[(size_t)row * N_FEAT]);         \
            v = CHI[r] * w; v = (fabsf(v) > THRESH) ? v : 0.f;                 \
            __builtin_nontemporal_store(v, &ob[(size_t)row * N_FEAT + 32]);    \
        }                                                                      \
    }
    STORE_TILE(c00, c01, 0)
    STORE_TILE(c10, c11, 1)
    STORE_TILE(c20, c21, 2)
    STORE_TILE(c30, c31, 3)
#undef STORE_TILE
}

// ---- host --------------------------------------------------------------------
extern "C" void kernel_launch(void* const* d_in, const int* in_sizes, int n_in,
                              void* d_out, int out_size, void* d_ws, size_t ws_size,
                              hipStream_t stream) {
    const float* sig    = (const float*)d_in[0];
    const float* mother = (const float*)d_in[1];
    const float* sw     = (const float*)d_in[2];
    float* out = (float*)d_out;

    ushort_t* Atab = (ushort_t*)((char*)d_ws + 32768);   // 472 KB (<= 480 KB slot)
    ushort_t* XTc  = (ushort_t*)((char*)d_ws + 524288);  // 12.58 MB

    ScaleParams p;
    int aoff = 0;
    for (int i = 0; i < N_SCALES; ++i) {
        double scale = pow(10.0, (double)i * log10(32.0) / 7.0);
        double v = 64.0 * scale;
        double r = floor(v + 0.5);
        int L = (fabs(v - r) < 1e-6) ? (int)r : (int)v;
        p.L[i] = L;
        p.Mc[i] = (L + 46) >> 4;                 // ceil((L+31)/16)
        p.Niter[i] = (p.Mc[i] + 13) & ~7;        // Mc+6 rounded up to x8
        p.Aoff[i] = aoff;
        aoff += (p.Niter[i] + 8) * 512;          // 6 lead zeros + real + tail zeros
        p.inv_sqrt_scale[i] = (float)(1.0 / sqrt(scale));
        p.step[i] = (float)(63.0 / (double)(L - 1));
    }
    const int totalA = aoff;                     // 472*512 elems

    prep_A<<<dim3((totalA + 255) / 256), dim3(256), 0, stream>>>(
        mother, Atab, p, totalA);
    transpose_sig<<<dim3((PADL + S_LEN) / 32, N_BATCH), dim3(256), 0, stream>>>(
        sig, XTc);

    wavelet_mfma<<<dim3(S_LEN / 512, N_BATCH, N_SCALES), dim3(256), 0, stream>>>(
        XTc, Atab, sw, out, p);
}

// Round 6
// 71.444 us; speedup vs baseline: 1.2307x; 1.2307x over previous
//
#include <hip/hip_runtime.h>
#include <hip/hip_bf16.h>
#include <math.h>

#define S_LEN 4096
#define N_FEAT 64
#define N_BATCH 16
#define N_SCALES 8
#define THRESH 1e-4f
#define PADL 2048
#define NCHUNK ((PADL + S_LEN) / 16)    // 384 chunks of 16 s-values
#define BCHUNK_ELEMS 1024               // [h:2][f:64][e:8] bf16 per 16-s chunk

typedef unsigned short ushort_t;
typedef __attribute__((ext_vector_type(8))) short bf16x8;
typedef __attribute__((ext_vector_type(16))) float f32x16;

struct ScaleParams {
    int L[N_SCALES], Mc[N_SCALES], Niter[N_SCALES], Aoff[N_SCALES]; // Aoff: ushort elems
    float inv_sqrt_scale[N_SCALES], step[N_SCALES];
};

// ---- prep: Toeplitz A-matrices in MFMA A-frag order, interp fused ------------
// Scale table: NC = Niter+8 chunks; chunk ci <-> conv chunk m = ci-6
// A_m[ti][sj] = kern[16m-16+ti-sj]; kern[l] = interp(mother, l*step)*inv_sqrt
__global__ void prep_A(const float* __restrict__ mother, ushort_t* __restrict__ Atab,
                       ScaleParams p, int totalA) {
    int i = blockIdx.x * blockDim.x + threadIdx.x;
    if (i >= totalA) return;
    int idx = 0;
#pragma unroll
    for (int s = 1; s < N_SCALES; ++s)
        if (i >= p.Aoff[s]) idx = s;
    int rel = i - p.Aoff[idx];
    int ci = rel >> 9;
    int r = rel & 511;
    int lane = r >> 3, e = r & 7;
    int ti = lane & 31, sj = 8 * (lane >> 5) + e;
    int kidx = 16 * (ci - 6) - 16 + ti - sj;
    float v = 0.f;
    if (kidx >= 0 && kidx < p.L[idx]) {
        float xq = fminf(kidx * p.step[idx], 63.0f);
        int i0 = (int)xq; if (i0 > 62) i0 = 62;
        float frac = xq - (float)i0;
        float a = mother[idx * 64 + i0];
        float b = mother[idx * 64 + i0 + 1];
        v = (a + (b - a) * frac) * p.inv_sqrt_scale[idx];
    }
    __hip_bfloat16 hh = __float2bfloat16(v);
    Atab[i] = *reinterpret_cast<ushort_t*>(&hh);
}

// ---- prep: signal [b][s][f] fp32 -> fragment-major XTc[b][G][f][e] bf16 ------
__global__ __launch_bounds__(256) void transpose_sig(const float* __restrict__ sig,
                                                     ushort_t* __restrict__ XTc) {
    const int b = blockIdx.y;
    const int G = blockIdx.x * 4 + (threadIdx.x >> 6);
    const int l = threadIdx.x & 63;
    unsigned int u[4];
    if (G < PADL / 8) {
        u[0] = u[1] = u[2] = u[3] = 0u;
    } else {
        const float* sp = sig + ((size_t)b * S_LEN + ((size_t)G * 8 - PADL)) * N_FEAT + l;
#pragma unroll
        for (int j = 0; j < 4; ++j) {
            float v0 = sp[(size_t)(2 * j) * N_FEAT];
            float v1 = sp[(size_t)(2 * j + 1) * N_FEAT];
            __hip_bfloat16 h0 = __float2bfloat16(v0);
            __hip_bfloat16 h1 = __float2bfloat16(v1);
            u[j] = (unsigned int)*reinterpret_cast<ushort_t*>(&h0) |
                   ((unsigned int)*reinterpret_cast<ushort_t*>(&h1) << 16);
        }
    }
    uint4 vv = {u[0], u[1], u[2], u[3]};
    *reinterpret_cast<uint4*>(XTc + (size_t)b * (NCHUNK * BCHUNK_ELEMS)
                              + (size_t)G * 512 + l * 8) = vv;
}

#define MFMA(A, X, C) C = __builtin_amdgcn_mfma_f32_32x32x16_bf16(A, X, C, 0, 0, 0)

// ---- main conv: 1 wave = 128 t x 64 f; A-ring(8) + depth-4 B ring ------------
// 1-D grid, XCD-bijective swizzle: xcd = n&7 owns b in {2*xcd, 2*xcd+1};
// within each XCD stream scales run heavy-first (idx 7 -> 0).
__global__ __launch_bounds__(256) void wavelet_mfma(
    const ushort_t* __restrict__ XTc, const ushort_t* __restrict__ Atab,
    const float* __restrict__ sw, float* __restrict__ out, ScaleParams p) {
    const int n = blockIdx.x;                 // 0..1023
    const int xcd = n & 7;
    const int r = n >> 3;                     // 0..127
    const int b = 2 * xcd + (r & 1);
    const int q = r >> 1;                     // 0..63
    const int xblk = q & 7;
    const int idx = 7 - (q >> 3);             // heavy scales first per XCD

    const int wave = threadIdx.x >> 6, lane = threadIdx.x & 63;
    const int tw0 = xblk * 512 + wave * 128;
    const int h = lane >> 5, fc = lane & 31;
    const int niter = p.Niter[idx];
    const int c0 = (PADL + tw0) / 16 + 1;

    const ushort_t* Ab = Atab + p.Aoff[idx] + lane * 8;              // A chunk ci: +ci*512
    const ushort_t* Bb = XTc + (size_t)b * (NCHUNK * BCHUNK_ELEMS)
                       + h * 512 + fc * 8;                            // B chunk c: +c*1024

    f32x16 c00, c01, c10, c11, c20, c21, c30, c31;
#pragma unroll
    for (int i = 0; i < 16; ++i) {
        c00[i] = 0.f; c01[i] = 0.f; c10[i] = 0.f; c11[i] = 0.f;
        c20[i] = 0.f; c21[i] = 0.f; c30[i] = 0.f; c31[i] = 0.f;
    }

    // preload A ring (chunks 0..7; 0..5 leading zero pad) and B ring depth-4
    bf16x8 Ar[8];
#pragma unroll
    for (int i = 0; i < 8; ++i)
        Ar[i] = *reinterpret_cast<const bf16x8*>(Ab + i * 512);
    bf16x8 Xr0[4], Xr1[4];
#pragma unroll
    for (int i = 0; i < 4; ++i) {             // slot i <- chunk c0+6-i
        const ushort_t* q0 = Bb + (size_t)(c0 + 6 - i) * 1024;
        Xr0[i] = *reinterpret_cast<const bf16x8*>(q0);
        Xr1[i] = *reinterpret_cast<const bf16x8*>(q0 + 256);
    }

    const ushort_t* Apf = Ab + 8 * 512;                   // A chunk n+8
    const ushort_t* Bpf = Bb + (size_t)(c0 + 2) * 1024;   // B chunk for phase n+4

    for (int it = 0; it < niter; it += 8) {
#pragma unroll
        for (int ph = 0; ph < 8; ++ph) {
            bf16x8 a0 = Ar[ph & 7];          // chunk n      (subtile j=0)
            bf16x8 a1 = Ar[(ph + 2) & 7];    // chunk n+2    (j=1)
            bf16x8 a2 = Ar[(ph + 4) & 7];    // chunk n+4    (j=2)
            bf16x8 a3 = Ar[(ph + 6) & 7];    // chunk n+6    (j=3)
            bf16x8 x0 = Xr0[ph & 3];
            bf16x8 x1 = Xr1[ph & 3];
            // prefetch into the slots freed this phase
            Ar[ph & 7] = *reinterpret_cast<const bf16x8*>(Apf);
            Apf += 512;
            Xr0[ph & 3] = *reinterpret_cast<const bf16x8*>(Bpf);
            Xr1[ph & 3] = *reinterpret_cast<const bf16x8*>(Bpf + 256);
            Bpf -= 1024;
            MFMA(a0, x0, c00); MFMA(a0, x1, c01);
            MFMA(a1, x0, c10); MFMA(a1, x1, c11);
            MFMA(a2, x0, c20); MFMA(a2, x1, c21);
            MFMA(a3, x0, c30); MFMA(a3, x1, c31);
        }
    }

    const float w = sw[idx];
    float* ob = out + ((size_t)(b * N_SCALES + idx) * S_LEN + tw0) * N_FEAT + fc;
#define STORE_TILE(CLO, CHI, JT)                                               \
    {                                                                          \
        _Pragma("unroll") for (int i = 0; i < 16; ++i) {                       \
            const int row = (JT) * 32 + (i & 3) + 8 * (i >> 2) + 4 * h;        \
            float v;                                                           \
            v = CLO[i] * w; v = (fabsf(v) > THRESH) ? v : 0.f;                 \
            __builtin_nontemporal_store(v, &ob[(size_t)row * N_FEAT]);         \
            v = CHI[i] * w; v = (fabsf(v) > THRESH) ? v : 0.f;                 \
            __builtin_nontemporal_store(v, &ob[(size_t)row * N_FEAT + 32]);    \
        }                                                                      \
    }
    STORE_TILE(c00, c01, 0)
    STORE_TILE(c10, c11, 1)
    STORE_TILE(c20, c21, 2)
    STORE_TILE(c30, c31, 3)
#undef STORE_TILE
}

// ---- host --------------------------------------------------------------------
extern "C" void kernel_launch(void* const* d_in, const int* in_sizes, int n_in,
                              void* d_out, int out_size, void* d_ws, size_t ws_size,
                              hipStream_t stream) {
    const float* sig    = (const float*)d_in[0];
    const float* mother = (const float*)d_in[1];
    const float* sw     = (const float*)d_in[2];
    float* out = (float*)d_out;

    ushort_t* Atab = (ushort_t*)((char*)d_ws + 32768);   // ~472 KB
    ushort_t* XTc  = (ushort_t*)((char*)d_ws + 524288);  // 12.58 MB

    ScaleParams p;
    int aoff = 0;
    for (int i = 0; i < N_SCALES; ++i) {
        double scale = pow(10.0, (double)i * log10(32.0) / 7.0);
        double v = 64.0 * scale;
        double r = floor(v + 0.5);
        int L = (fabs(v - r) < 1e-6) ? (int)r : (int)v;
        p.L[i] = L;
        p.Mc[i] = (L + 46) >> 4;                 // ceil((L+31)/16)
        p.Niter[i] = (p.Mc[i] + 13) & ~7;        // Mc+6 rounded up to x8
        p.Aoff[i] = aoff;
        aoff += (p.Niter[i] + 8) * 512;          // 6 lead zeros + real + tail zeros
        p.inv_sqrt_scale[i] = (float)(1.0 / sqrt(scale));
        p.step[i] = (float)(63.0 / (double)(L - 1));
    }
    const int totalA = aoff;

    prep_A<<<dim3((totalA + 255) / 256), dim3(256), 0, stream>>>(
        mother, Atab, p, totalA);
    transpose_sig<<<dim3((PADL + S_LEN) / 32, N_BATCH), dim3(256), 0, stream>>>(
        sig, XTc);

    wavelet_mfma<<<dim3(S_LEN / 512 * N_BATCH * N_SCALES), dim3(256), 0, stream>>>(
        XTc, Atab, sw, out, p);
}